// Round 10
// baseline (117.081 us; speedup 1.0000x reference)
//
#include <hip/hip_runtime.h>

#define IS 256
#define FCOUNT 4096
#define NEARP 0.1f
#define FARP 100.0f
#define TINYF 1e-12f
#define CAP 256          // per-tile list capacity (counts<=256 validated R8/R9)
#define GCAP 128         // per-image sliver-list capacity (expect ~<8)
#define DET_GLOBAL 1e-5f // |det| below this -> per-image list (escape unbounded)

// Value barrier: pins a value in a VGPR; no transform across it.
__device__ __forceinline__ float frn(float r) { asm("" : "+v"(r)); return r; }
__device__ __forceinline__ float mulrn(float a, float b) { return frn(a * b); }
__device__ __forceinline__ float addrn(float a, float b) { return frn(a + b); }
__device__ __forceinline__ float subrn(float a, float b) { return frn(a - b); }
__device__ __forceinline__ float divrn(float a, float b) { return frn(a / b); }
__device__ __forceinline__ float fmarn(float a, float b, float c) {
    return frn(__builtin_fmaf(a, b, c));
}

// ---------- pass 1: per-face constants + bin into 16x16-px tiles ----------
// Constants use the R6-verified contracted numerics (computed ONCE per face,
// reused by every tile scan). Escape bound: fp-inside region extends
// <= ~6e-8/|det| beyond the hull; dilate 2e-3 + 3e-7/|det| (5x safety,
// <= 0.032). |det| < 1e-5 -> one atomic into the per-image global list.
__global__ __launch_bounds__(256) void bin_kernel(
    const float* __restrict__ faces,
    float4* __restrict__ cA, float4* __restrict__ cB, float4* __restrict__ cC,
    int* __restrict__ counts, int* __restrict__ lists,
    int* __restrict__ gcount, int* __restrict__ glist, int B, int F)
{
    const int gid = blockIdx.x * 256 + threadIdx.x;
    if (gid >= B * F) return;
    const int b = gid >> 12, f = gid & (FCOUNT - 1);   // F == 4096
    const float* fp = faces + (size_t)gid * 9;
    const float x0 = fp[0], y0 = fp[1], z0 = fp[2];
    const float x1 = fp[3], y1 = fp[4], z1 = fp[5];
    const float x2 = fp[6], y2 = fp[7], z2 = fp[8];

    // Verified contracted numerics: C = fma(xa, yb, -(xb*ya)).
    const float A0 = subrn(x2, x1), B0 = subrn(y1, y2);
    const float C0 = fmarn(x1, y2, -mulrn(x2, y1));
    const float A1 = subrn(x0, x2), B1 = subrn(y2, y0);
    const float C1 = fmarn(x2, y0, -mulrn(x0, y2));
    const float A2 = subrn(x1, x0), B2 = subrn(y0, y1);
    const float C2 = fmarn(x0, y1, -mulrn(x1, y0));
    cA[gid] = make_float4(A0, B0, C0, A1);
    cB[gid] = make_float4(B1, C1, A2, B2);
    cC[gid] = make_float4(C2, z0, z1, z2);

    // Conservative dilation (plain math fine here).
    const float det = (x1 - x0) * (y2 - y0) - (x2 - x0) * (y1 - y0);
    const float ad = fabsf(det);
    if (ad < DET_GLOBAL) {
        const int pos = atomicAdd(&gcount[b], 1);
        if (pos < GCAP) glist[b * GCAP + pos] = f;
        return;
    }
    const float d = 2e-3f + 3e-7f / ad;   // <= 0.032
    const float lox = fminf(x0, fminf(x1, x2)) - d;
    const float hix = fmaxf(x0, fmaxf(x1, x2)) + d;
    const float loy = fminf(y0, fminf(y1, y2)) - d;
    const float hiy = fmaxf(y0, fmaxf(y1, y2)) + d;
    // tile t spans NDC [(32t+1-256)/256, (32t+31-256)/256]; floor(+255) is a
    // proven superset of the exact ceil/floor bounds (R9-validated).
    int tx0 = (int)floorf((256.f * lox + 255.f) * (1.f / 32.f));
    int tx1 = (int)floorf((256.f * hix + 255.f) * (1.f / 32.f));
    int ty0 = (int)floorf((256.f * loy + 255.f) * (1.f / 32.f));
    int ty1 = (int)floorf((256.f * hiy + 255.f) * (1.f / 32.f));
    tx0 = max(tx0, 0); tx1 = min(tx1, 15);
    ty0 = max(ty0, 0); ty1 = min(ty1, 15);
    for (int ty = ty0; ty <= ty1; ++ty)
        for (int tx = tx0; tx <= tx1; ++tx) {
            const int t = (b * 16 + ty) * 16 + tx;
            const int pos = atomicAdd(&counts[t], 1);
            if (pos < CAP) lists[(size_t)t * CAP + pos] = f;
        }
}

// ---------- pass 2: rasterize each tile — scalar-pipe face streaming ----------
// No LDS, no __syncthreads: the scan index j is wave-uniform, so face id and
// the three float4 constants are uniform loads (scalar cache; the 4 waves of
// a block reuse the same ~5 KB stream). readfirstlane pins uniformity.
// Numerics: R6-verified contracted chain. Tie-break: smallest zp, then
// smallest face index (== reference chunked argmin).
__global__ __launch_bounds__(256) void raster_kernel(
    const float* __restrict__ faces,
    const float* __restrict__ textures,
    const float4* __restrict__ cA, const float4* __restrict__ cB,
    const float4* __restrict__ cC,
    const int* __restrict__ counts, const int* __restrict__ lists,
    const int* __restrict__ gcount, const int* __restrict__ glist,
    float* __restrict__ out, int B, int F)
{
    const int tid  = threadIdx.x;
    const int b    = blockIdx.x >> 8;
    const int tile = blockIdx.x & 255;
    const int px   = (tile & 15) * 16 + (tid & 15);
    const int py   = (tile >> 4) * 16 + (tid >> 4);
    const float xp = (float)(2 * px + 1 - IS) * (1.0f / IS);  // exact (/2^8)
    const float yp = (float)(2 * py + 1 - IS) * (1.0f / IS);  // exact

    float bestz = FARP;
    int   besti = -1;

    const int cnt  = min(counts[blockIdx.x], CAP);
    const int gcnt = min(gcount[b], GCAP);
    const int total = cnt + gcnt;
    const int* mylist = lists + (size_t)blockIdx.x * CAP;
    const int* gl     = glist + b * GCAP;
    const int fb = b * F;

    for (int j = 0; j < total; ++j) {
        const int fid = (j < cnt) ? mylist[j] : gl[j - cnt];
        const int f = __builtin_amdgcn_readfirstlane(fid);
        const float4 fa = cA[fb + f];
        const float4 fb4 = cB[fb + f];
        const float4 fc = cC[fb + f];
        // Contracted: w = fma(yp, A, xp*B) + C
        const float w0 = addrn(fmarn(yp, fa.x, mulrn(xp, fa.y)), fa.z);
        const float w1 = addrn(fmarn(yp, fa.w, mulrn(xp, fb4.x)), fb4.y);
        const float w2 = addrn(fmarn(yp, fb4.z, mulrn(xp, fb4.w)), fc.x);
        const float det = addrn(addrn(w0, w1), w2);
        bool ins;
        if (det > TINYF)       ins = (w0 > 0.f) && (w1 > 0.f) && (w2 > 0.f);
        else if (det < -TINYF) ins = (w0 < 0.f) && (w1 < 0.f) && (w2 < 0.f);
        else                   ins = false;
        if (ins) {
            float n0 = divrn(w0, det), n1 = divrn(w1, det), n2 = divrn(w2, det);
            n0 = frn(fminf(fmaxf(n0, 0.f), 1.f));
            n1 = frn(fminf(fmaxf(n1, 0.f), 1.f));
            n2 = frn(fminf(fmaxf(n2, 0.f), 1.f));
            float s = addrn(addrn(n0, n1), n2);
            s = (s > TINYF) ? s : 1.0f;
            n0 = divrn(n0, s); n1 = divrn(n1, s); n2 = divrn(n2, s);
            float iz = addrn(addrn(divrn(n0, fc.y), divrn(n1, fc.z)),
                             divrn(n2, fc.w));
            iz = (fabsf(iz) > TINYF) ? iz : 1.0f;
            const float zp = divrn(1.0f, iz);
            if (zp > NEARP && zp < FARP) {
                if (zp < bestz || (zp == bestz && f < besti)) {
                    bestz = zp;
                    besti = f;
                }
            }
        }
    }

    // Phase C: shade the winning face (R6-verified chain, unchanged).
    const float* fbase = faces + (size_t)b * F * 9;
    float r = 0.f, g = 0.f, bch = 0.f, alpha = 0.f, depth = FARP;
    if (besti >= 0) {
        const float* fp = fbase + (size_t)besti * 9;
        const float x0 = fp[0], y0 = fp[1], z0 = fp[2];
        const float x1 = fp[3], y1 = fp[4], z1 = fp[5];
        const float x2 = fp[6], y2 = fp[7], z2 = fp[8];
        const float w0 = addrn(fmarn(yp, subrn(x2, x1), mulrn(xp, subrn(y1, y2))),
                               fmarn(x1, y2, -mulrn(x2, y1)));
        const float w1 = addrn(fmarn(yp, subrn(x0, x2), mulrn(xp, subrn(y2, y0))),
                               fmarn(x2, y0, -mulrn(x0, y2)));
        const float w2 = addrn(fmarn(yp, subrn(x1, x0), mulrn(xp, subrn(y0, y1))),
                               fmarn(x0, y1, -mulrn(x1, y0)));
        const float det = addrn(addrn(w0, w1), w2);
        const float sd = (fabsf(det) > TINYF) ? det : 1.0f;
        float n0 = divrn(w0, sd), n1 = divrn(w1, sd), n2 = divrn(w2, sd);
        n0 = frn(fminf(fmaxf(n0, 0.f), 1.f));
        n1 = frn(fminf(fmaxf(n1, 0.f), 1.f));
        n2 = frn(fminf(fmaxf(n2, 0.f), 1.f));
        float s = addrn(addrn(n0, n1), n2);
        s = (s > TINYF) ? s : 1.0f;
        n0 = divrn(n0, s); n1 = divrn(n1, s); n2 = divrn(n2, s);
        float iz = addrn(addrn(divrn(n0, z0), divrn(n1, z1)), divrn(n2, z2));
        iz = (fabsf(iz) > TINYF) ? iz : 1.0f;
        const float zp = divrn(1.0f, iz);
        depth = zp;

        const float t0 = fminf(fmaxf(divrn(mulrn(mulrn(n0, 3.0f), zp), z0), 0.f), 2.999f);
        const float t1 = fminf(fmaxf(divrn(mulrn(mulrn(n1, 3.0f), zp), z1), 0.f), 2.999f);
        const float t2 = fminf(fmaxf(divrn(mulrn(mulrn(n2, 3.0f), zp), z2), 0.f), 2.999f);
        const float l0 = floorf(t0), l1 = floorf(t1), l2 = floorf(t2);
        const float fr0 = subrn(t0, l0), fr1 = subrn(t1, l1), fr2 = subrn(t2, l2);
        const int i0 = (int)l0, i1 = (int)l1, i2 = (int)l2;

        const float* tx = textures + (size_t)(b * F + besti) * 64 * 3;
        for (int d0 = 0; d0 < 2; ++d0)
            for (int d1 = 0; d1 < 2; ++d1)
                for (int d2 = 0; d2 < 2; ++d2) {
                    const float wg = mulrn(mulrn(d0 ? fr0 : subrn(1.0f, fr0),
                                                 d1 ? fr1 : subrn(1.0f, fr1)),
                                           d2 ? fr2 : subrn(1.0f, fr2));
                    const float* tp = tx + ((i0 + d0) * 16 + (i1 + d1) * 4 + (i2 + d2)) * 3;
                    r   = addrn(r,   mulrn(wg, tp[0]));
                    g   = addrn(g,   mulrn(wg, tp[1]));
                    bch = addrn(bch, mulrn(wg, tp[2]));
                }
        alpha = 1.0f;
    }

    float* op = out + (((size_t)b * IS + py) * IS + px) * 5;
    op[0] = r;
    op[1] = g;
    op[2] = bch;
    op[3] = alpha;
    op[4] = depth;
}

extern "C" void kernel_launch(void* const* d_in, const int* in_sizes, int n_in,
                              void* d_out, int out_size, void* d_ws, size_t ws_size,
                              hipStream_t stream) {
    const float* faces    = (const float*)d_in[0];
    const float* textures = (const float*)d_in[1];
    float* out = (float*)d_out;
    const int F = FCOUNT;
    const int B = in_sizes[0] / (F * 9);
    const int ntiles = B * 256;

    // ws layout (16B-aligned at cA: byte offsets all multiples of 16)
    int* counts = (int*)d_ws;                       // ntiles ints
    int* gcount = counts + ntiles;                  // B ints
    int* glist  = gcount + B;                       // B*GCAP ints
    int* lists  = glist + B * GCAP;                 // ntiles*CAP ints
    float4* cA  = (float4*)(lists + (size_t)ntiles * CAP);   // B*F float4
    float4* cB  = cA + (size_t)B * F;
    float4* cC  = cB + (size_t)B * F;

    // zero counts + gcount in one async memset (contiguous)
    hipMemsetAsync(counts, 0, (size_t)(ntiles + B) * sizeof(int), stream);
    bin_kernel<<<dim3((B * F + 255) / 256), dim3(256), 0, stream>>>(
        faces, cA, cB, cC, counts, lists, gcount, glist, B, F);
    raster_kernel<<<dim3(ntiles), dim3(256), 0, stream>>>(
        faces, textures, cA, cB, cC, counts, lists, gcount, glist, out, B, F);
}

// Round 11
// 109.098 us; speedup vs baseline: 1.0732x; 1.0732x over previous
//
#include <hip/hip_runtime.h>

#define IS 256
#define FCOUNT 4096
#define NEARP 0.1f
#define FARP 100.0f
#define TINYF 1e-12f
#define CAP 256          // per-tile list capacity (counts ~85 mean, R8/R9 validated)
#define GCAP 128         // per-image sliver-list capacity
#define DET_GLOBAL 1e-5f // |det| below this -> per-image list (escape unbounded)

// Value barrier: pins a value in a VGPR; no transform across it.
__device__ __forceinline__ float frn(float r) { asm("" : "+v"(r)); return r; }
__device__ __forceinline__ float mulrn(float a, float b) { return frn(a * b); }
__device__ __forceinline__ float addrn(float a, float b) { return frn(a + b); }
__device__ __forceinline__ float subrn(float a, float b) { return frn(a - b); }
__device__ __forceinline__ float divrn(float a, float b) { return frn(a / b); }
__device__ __forceinline__ float fmarn(float a, float b, float c) {
    return frn(__builtin_fmaf(a, b, c));
}

// ---------- pass 1: per-face constants + bin into 16x16-px tiles ----------
// 64-thread blocks -> 256 blocks: spreads binning over all CUs (R10 ran on 64).
// Constants: R6-verified contracted numerics, computed ONCE per face.
// Escape bound: fp-inside region extends <= ~6e-8/|det| beyond the hull;
// dilate 2e-3 + 3e-7/|det| (5x safety, <= 0.032). |det| < 1e-5 -> one atomic
// into the per-image global list (avoids R8's 256-atomic sliver pathology).
__global__ __launch_bounds__(64) void bin_kernel(
    const float* __restrict__ faces,
    float4* __restrict__ cA, float4* __restrict__ cB, float4* __restrict__ cC,
    int* __restrict__ counts, int* __restrict__ lists,
    int* __restrict__ gcount, int* __restrict__ glist, int B, int F)
{
    const int gid = blockIdx.x * 64 + threadIdx.x;
    if (gid >= B * F) return;
    const int b = gid >> 12, f = gid & (FCOUNT - 1);   // F == 4096
    const float* fp = faces + (size_t)gid * 9;
    const float x0 = fp[0], y0 = fp[1], z0 = fp[2];
    const float x1 = fp[3], y1 = fp[4], z1 = fp[5];
    const float x2 = fp[6], y2 = fp[7], z2 = fp[8];

    // Verified contracted numerics: C = fma(xa, yb, -(xb*ya)).
    const float A0 = subrn(x2, x1), B0 = subrn(y1, y2);
    const float C0 = fmarn(x1, y2, -mulrn(x2, y1));
    const float A1 = subrn(x0, x2), B1 = subrn(y2, y0);
    const float C1 = fmarn(x2, y0, -mulrn(x0, y2));
    const float A2 = subrn(x1, x0), B2 = subrn(y0, y1);
    const float C2 = fmarn(x0, y1, -mulrn(x1, y0));
    cA[gid] = make_float4(A0, B0, C0, A1);
    cB[gid] = make_float4(B1, C1, A2, B2);
    cC[gid] = make_float4(C2, z0, z1, z2);

    // Conservative dilation (plain math fine here).
    const float det = (x1 - x0) * (y2 - y0) - (x2 - x0) * (y1 - y0);
    const float ad = fabsf(det);
    if (ad < DET_GLOBAL) {
        const int pos = atomicAdd(&gcount[b], 1);
        if (pos < GCAP) glist[b * GCAP + pos] = f;
        return;
    }
    const float d = 2e-3f + 3e-7f / ad;   // <= 0.032
    const float lox = fminf(x0, fminf(x1, x2)) - d;
    const float hix = fmaxf(x0, fmaxf(x1, x2)) + d;
    const float loy = fminf(y0, fminf(y1, y2)) - d;
    const float hiy = fmaxf(y0, fmaxf(y1, y2)) + d;
    // tile t spans NDC [(32t+1-256)/256, (32t+31-256)/256]; floor(+255) is a
    // proven superset of the exact bounds (R9/R10-validated).
    int tx0 = (int)floorf((256.f * lox + 255.f) * (1.f / 32.f));
    int tx1 = (int)floorf((256.f * hix + 255.f) * (1.f / 32.f));
    int ty0 = (int)floorf((256.f * loy + 255.f) * (1.f / 32.f));
    int ty1 = (int)floorf((256.f * hiy + 255.f) * (1.f / 32.f));
    tx0 = max(tx0, 0); tx1 = min(tx1, 15);
    ty0 = max(ty0, 0); ty1 = min(ty1, 15);
    for (int ty = ty0; ty <= ty1; ++ty)
        for (int tx = tx0; tx <= tx1; ++tx) {
            const int t = (b * 16 + ty) * 16 + tx;
            const int pos = atomicAdd(&counts[t], 1);
            if (pos < CAP) lists[(size_t)t * CAP + pos] = f;
        }
}

// ---------- pass 2: rasterize each tile from its bin (LDS-staged scan) ------
// R8-proven structure: stage the tile's face constants into LDS with
// coalesced float4 loads (from the precomputed cA/cB/cC), then every pixel
// scans with broadcast ds_read_b128 (conflict-free). Numerics: R6-verified
// contracted chain. Tie-break: smallest zp, then smallest face index
// (== reference chunked argmin, independent of bin order).
__global__ __launch_bounds__(256) void raster_kernel(
    const float* __restrict__ faces,
    const float* __restrict__ textures,
    const float4* __restrict__ cA, const float4* __restrict__ cB,
    const float4* __restrict__ cC,
    const int* __restrict__ counts, const int* __restrict__ lists,
    const int* __restrict__ gcount, const int* __restrict__ glist,
    float* __restrict__ out, int B, int F)
{
    const int tid  = threadIdx.x;
    const int b    = blockIdx.x >> 8;
    const int tile = blockIdx.x & 255;
    const int px   = (tile & 15) * 16 + (tid & 15);
    const int py   = (tile >> 4) * 16 + (tid >> 4);
    const float xp = (float)(2 * px + 1 - IS) * (1.0f / IS);  // exact (/2^8)
    const float yp = (float)(2 * py + 1 - IS) * (1.0f / IS);  // exact

    __shared__ float4 s_a[256];   // A0,B0,C0,A1
    __shared__ float4 s_b[256];   // B1,C1,A2,B2
    __shared__ float4 s_c[256];   // C2,z0,z1,z2
    __shared__ int    s_idx[256];

    float bestz = FARP;
    int   besti = -1;

    const int cnt  = min(counts[blockIdx.x], CAP);
    const int gcnt = min(gcount[b], GCAP);
    const int total = cnt + gcnt;
    const int* mylist = lists + (size_t)blockIdx.x * CAP;
    const int* gl     = glist + b * GCAP;
    const int fb = b * F;

    for (int cbase = 0; cbase < total; cbase += 256) {
        const int m = min(total - cbase, 256);
        if (tid < m) {
            const int k = cbase + tid;
            const int f = (k < cnt) ? mylist[k] : gl[k - cnt];
            s_a[tid] = cA[fb + f];
            s_b[tid] = cB[fb + f];
            s_c[tid] = cC[fb + f];
            s_idx[tid] = f;
        }
        __syncthreads();

        for (int j = 0; j < m; ++j) {
            const float4 fa = s_a[j];
            const float4 fb4 = s_b[j];
            const float4 fc = s_c[j];
            // Contracted: w = fma(yp, A, xp*B) + C
            const float w0 = addrn(fmarn(yp, fa.x, mulrn(xp, fa.y)), fa.z);
            const float w1 = addrn(fmarn(yp, fa.w, mulrn(xp, fb4.x)), fb4.y);
            const float w2 = addrn(fmarn(yp, fb4.z, mulrn(xp, fb4.w)), fc.x);
            const float det = addrn(addrn(w0, w1), w2);
            bool ins;
            if (det > TINYF)       ins = (w0 > 0.f) && (w1 > 0.f) && (w2 > 0.f);
            else if (det < -TINYF) ins = (w0 < 0.f) && (w1 < 0.f) && (w2 < 0.f);
            else                   ins = false;
            if (ins) {
                float n0 = divrn(w0, det), n1 = divrn(w1, det), n2 = divrn(w2, det);
                n0 = frn(fminf(fmaxf(n0, 0.f), 1.f));
                n1 = frn(fminf(fmaxf(n1, 0.f), 1.f));
                n2 = frn(fminf(fmaxf(n2, 0.f), 1.f));
                float s = addrn(addrn(n0, n1), n2);
                s = (s > TINYF) ? s : 1.0f;
                n0 = divrn(n0, s); n1 = divrn(n1, s); n2 = divrn(n2, s);
                float iz = addrn(addrn(divrn(n0, fc.y), divrn(n1, fc.z)),
                                 divrn(n2, fc.w));
                iz = (fabsf(iz) > TINYF) ? iz : 1.0f;
                const float zp = divrn(1.0f, iz);
                if (zp > NEARP && zp < FARP) {
                    const int fi = s_idx[j];
                    if (zp < bestz || (zp == bestz && fi < besti)) {
                        bestz = zp;
                        besti = fi;
                    }
                }
            }
        }
        __syncthreads();
    }

    // Phase C: shade the winning face (R6-verified chain, unchanged).
    const float* fbase = faces + (size_t)b * F * 9;
    float r = 0.f, g = 0.f, bch = 0.f, alpha = 0.f, depth = FARP;
    if (besti >= 0) {
        const float* fp = fbase + (size_t)besti * 9;
        const float x0 = fp[0], y0 = fp[1], z0 = fp[2];
        const float x1 = fp[3], y1 = fp[4], z1 = fp[5];
        const float x2 = fp[6], y2 = fp[7], z2 = fp[8];
        const float w0 = addrn(fmarn(yp, subrn(x2, x1), mulrn(xp, subrn(y1, y2))),
                               fmarn(x1, y2, -mulrn(x2, y1)));
        const float w1 = addrn(fmarn(yp, subrn(x0, x2), mulrn(xp, subrn(y2, y0))),
                               fmarn(x2, y0, -mulrn(x0, y2)));
        const float w2 = addrn(fmarn(yp, subrn(x1, x0), mulrn(xp, subrn(y0, y1))),
                               fmarn(x0, y1, -mulrn(x1, y0)));
        const float det = addrn(addrn(w0, w1), w2);
        const float sd = (fabsf(det) > TINYF) ? det : 1.0f;
        float n0 = divrn(w0, sd), n1 = divrn(w1, sd), n2 = divrn(w2, sd);
        n0 = frn(fminf(fmaxf(n0, 0.f), 1.f));
        n1 = frn(fminf(fmaxf(n1, 0.f), 1.f));
        n2 = frn(fminf(fmaxf(n2, 0.f), 1.f));
        float s = addrn(addrn(n0, n1), n2);
        s = (s > TINYF) ? s : 1.0f;
        n0 = divrn(n0, s); n1 = divrn(n1, s); n2 = divrn(n2, s);
        float iz = addrn(addrn(divrn(n0, z0), divrn(n1, z1)), divrn(n2, z2));
        iz = (fabsf(iz) > TINYF) ? iz : 1.0f;
        const float zp = divrn(1.0f, iz);
        depth = zp;

        const float t0 = fminf(fmaxf(divrn(mulrn(mulrn(n0, 3.0f), zp), z0), 0.f), 2.999f);
        const float t1 = fminf(fmaxf(divrn(mulrn(mulrn(n1, 3.0f), zp), z1), 0.f), 2.999f);
        const float t2 = fminf(fmaxf(divrn(mulrn(mulrn(n2, 3.0f), zp), z2), 0.f), 2.999f);
        const float l0 = floorf(t0), l1 = floorf(t1), l2 = floorf(t2);
        const float fr0 = subrn(t0, l0), fr1 = subrn(t1, l1), fr2 = subrn(t2, l2);
        const int i0 = (int)l0, i1 = (int)l1, i2 = (int)l2;

        const float* tx = textures + (size_t)(b * F + besti) * 64 * 3;
        for (int d0 = 0; d0 < 2; ++d0)
            for (int d1 = 0; d1 < 2; ++d1)
                for (int d2 = 0; d2 < 2; ++d2) {
                    const float wg = mulrn(mulrn(d0 ? fr0 : subrn(1.0f, fr0),
                                                 d1 ? fr1 : subrn(1.0f, fr1)),
                                           d2 ? fr2 : subrn(1.0f, fr2));
                    const float* tp = tx + ((i0 + d0) * 16 + (i1 + d1) * 4 + (i2 + d2)) * 3;
                    r   = addrn(r,   mulrn(wg, tp[0]));
                    g   = addrn(g,   mulrn(wg, tp[1]));
                    bch = addrn(bch, mulrn(wg, tp[2]));
                }
        alpha = 1.0f;
    }

    float* op = out + (((size_t)b * IS + py) * IS + px) * 5;
    op[0] = r;
    op[1] = g;
    op[2] = bch;
    op[3] = alpha;
    op[4] = depth;
}

extern "C" void kernel_launch(void* const* d_in, const int* in_sizes, int n_in,
                              void* d_out, int out_size, void* d_ws, size_t ws_size,
                              hipStream_t stream) {
    const float* faces    = (const float*)d_in[0];
    const float* textures = (const float*)d_in[1];
    float* out = (float*)d_out;
    const int F = FCOUNT;
    const int B = in_sizes[0] / (F * 9);
    const int ntiles = B * 256;

    // ws layout (cA 16B-aligned: all preceding sizes are multiples of 16B)
    int* counts = (int*)d_ws;                       // ntiles ints
    int* gcount = counts + ntiles;                  // B ints
    int* glist  = gcount + B;                       // B*GCAP ints
    int* lists  = glist + B * GCAP;                 // ntiles*CAP ints
    float4* cA  = (float4*)(lists + (size_t)ntiles * CAP);   // B*F float4
    float4* cB  = cA + (size_t)B * F;
    float4* cC  = cB + (size_t)B * F;

    hipMemsetAsync(counts, 0, (size_t)(ntiles + B) * sizeof(int), stream);
    bin_kernel<<<dim3((B * F + 63) / 64), dim3(64), 0, stream>>>(
        faces, cA, cB, cC, counts, lists, gcount, glist, B, F);
    raster_kernel<<<dim3(ntiles), dim3(256), 0, stream>>>(
        faces, textures, cA, cB, cC, counts, lists, gcount, glist, out, B, F);
}

// Round 12
// 99.573 us; speedup vs baseline: 1.1758x; 1.0957x over previous
//
#include <hip/hip_runtime.h>

#define IS 256
#define FCOUNT 4096
#define NEARP 0.1f
#define FARP 100.0f
#define TINYF 1e-12f
#define CAP 192          // per-8x8-bin capacity (mean ~25; Poisson tail ≪ CAP)
#define GCAP 128         // per-image sliver-list capacity
#define DET_GLOBAL 1e-5f // |det| below this -> per-image list (escape unbounded)
#define ZEPS 2e-4f       // early-z slack: zp >= min(z)-5e-5 proven; 4x margin

// Value barrier: pins a value in a VGPR; no transform across it.
__device__ __forceinline__ float frn(float r) { asm("" : "+v"(r)); return r; }
__device__ __forceinline__ float mulrn(float a, float b) { return frn(a * b); }
__device__ __forceinline__ float addrn(float a, float b) { return frn(a + b); }
__device__ __forceinline__ float subrn(float a, float b) { return frn(a - b); }
__device__ __forceinline__ float divrn(float a, float b) { return frn(a / b); }
__device__ __forceinline__ float fmarn(float a, float b, float c) {
    return frn(__builtin_fmaf(a, b, c));
}

// ---------- pass 1: per-face constants + bin into 8x8-px tiles (32x32) ------
// Constants: R6-verified contracted numerics, computed ONCE per face.
// Escape bound: fp-inside region extends <= ~6e-8/|det| beyond the hull;
// dilate 2e-3 + 3e-7/|det| (5x safety, <= 0.032). |det| < 1e-5 -> one atomic
// into the per-image global list.
__global__ __launch_bounds__(64) void bin_kernel(
    const float* __restrict__ faces,
    float4* __restrict__ cA, float4* __restrict__ cB, float4* __restrict__ cC,
    int* __restrict__ counts, int* __restrict__ lists,
    int* __restrict__ gcount, int* __restrict__ glist, int B, int F)
{
    const int gid = blockIdx.x * 64 + threadIdx.x;
    if (gid >= B * F) return;
    const int b = gid >> 12, f = gid & (FCOUNT - 1);   // F == 4096
    const float* fp = faces + (size_t)gid * 9;
    const float x0 = fp[0], y0 = fp[1], z0 = fp[2];
    const float x1 = fp[3], y1 = fp[4], z1 = fp[5];
    const float x2 = fp[6], y2 = fp[7], z2 = fp[8];

    // Verified contracted numerics: C = fma(xa, yb, -(xb*ya)).
    const float A0 = subrn(x2, x1), B0 = subrn(y1, y2);
    const float C0 = fmarn(x1, y2, -mulrn(x2, y1));
    const float A1 = subrn(x0, x2), B1 = subrn(y2, y0);
    const float C1 = fmarn(x2, y0, -mulrn(x0, y2));
    const float A2 = subrn(x1, x0), B2 = subrn(y0, y1);
    const float C2 = fmarn(x0, y1, -mulrn(x1, y0));
    cA[gid] = make_float4(A0, B0, C0, A1);
    cB[gid] = make_float4(B1, C1, A2, B2);
    cC[gid] = make_float4(C2, z0, z1, z2);

    const float det = (x1 - x0) * (y2 - y0) - (x2 - x0) * (y1 - y0);
    const float ad = fabsf(det);
    if (ad < DET_GLOBAL) {
        const int pos = atomicAdd(&gcount[b], 1);
        if (pos < GCAP) glist[b * GCAP + pos] = f;
        return;
    }
    const float d = 2e-3f + 3e-7f / ad;   // <= 0.032
    const float lox = fminf(x0, fminf(x1, x2)) - d;
    const float hix = fmaxf(x0, fmaxf(x1, x2)) + d;
    const float loy = fminf(y0, fminf(y1, y2)) - d;
    const float hiy = fmaxf(y0, fmaxf(y1, y2)) + d;
    // 8-px tile t: xp in [(16t+1-256)/256, (16t+15-256)/256].
    // Overlap: t >= (256*lo+241)/16 and t <= (256*hi+255)/16. Dilation d
    // (>=2e-3 = 0.5 NDC px) dwarfs the ~1e-7 fp slack of these bounds.
    int tx0 = (int)ceilf ((256.f * lox + 241.f) * (1.f / 16.f));
    int tx1 = (int)floorf((256.f * hix + 255.f) * (1.f / 16.f));
    int ty0 = (int)ceilf ((256.f * loy + 241.f) * (1.f / 16.f));
    int ty1 = (int)floorf((256.f * hiy + 255.f) * (1.f / 16.f));
    tx0 = max(tx0, 0); tx1 = min(tx1, 31);
    ty0 = max(ty0, 0); ty1 = min(ty1, 31);
    for (int ty = ty0; ty <= ty1; ++ty)
        for (int tx = tx0; tx <= tx1; ++tx) {
            const int t = (b * 32 + ty) * 32 + tx;
            const int pos = atomicAdd(&counts[t], 1);
            if (pos < CAP) lists[(size_t)t * CAP + pos] = f;
        }
}

// ---------- pass 2: rasterize — wave-private 8x8 quadrant scan -------------
// Block = 16x16 tile; wave w owns one 8x8 quadrant and scans THAT quadrant's
// bin (~25 faces) from wave-private LDS. No __syncthreads. Early-z: skip the
// 10-divide chain when min(z) > bestz + ZEPS (cannot win or tie). Numerics:
// R6-verified contracted chain; tie-break (zp, then smaller index) matches
// the reference's chunked argmin regardless of bin order.
__global__ __launch_bounds__(256) void raster_kernel(
    const float* __restrict__ faces,
    const float* __restrict__ textures,
    const float4* __restrict__ cA, const float4* __restrict__ cB,
    const float4* __restrict__ cC,
    const int* __restrict__ counts, const int* __restrict__ lists,
    const int* __restrict__ gcount, const int* __restrict__ glist,
    float* __restrict__ out, int B, int F)
{
    const int tid  = threadIdx.x;
    const int lane = tid & 63;
    const int w    = tid >> 6;
    const int b    = blockIdx.x >> 8;
    const int tile = blockIdx.x & 255;
    const int qtx  = 2 * (tile & 15) + (w & 1);    // 8-px tile coords (0..31)
    const int qty  = 2 * (tile >> 4) + (w >> 1);
    const int qbin = (b * 32 + qty) * 32 + qtx;
    const int px   = qtx * 8 + (lane & 7);
    const int py   = qty * 8 + (lane >> 3);
    const float xp = (float)(2 * px + 1 - IS) * (1.0f / IS);  // exact (/2^8)
    const float yp = (float)(2 * py + 1 - IS) * (1.0f / IS);  // exact

    __shared__ float4 s_a[4][64];
    __shared__ float4 s_b[4][64];
    __shared__ float4 s_c[4][64];
    __shared__ int    s_i[4][64];

    float bestz = FARP;
    int   besti = -1;

    const int cnt  = min(counts[qbin], CAP);
    const int gcnt = min(gcount[b], GCAP);
    const int total = cnt + gcnt;
    const int* mylist = lists + (size_t)qbin * CAP;
    const int* gl     = glist + b * GCAP;
    const int fb = b * F;

    for (int cb = 0; cb < total; cb += 64) {
        const int m = min(total - cb, 64);
        if (lane < m) {
            const int k = cb + lane;
            const int f = (k < cnt) ? mylist[k] : gl[k - cnt];
            s_a[w][lane] = cA[fb + f];
            s_b[w][lane] = cB[fb + f];
            s_c[w][lane] = cC[fb + f];
            s_i[w][lane] = f;
        }
        __builtin_amdgcn_wave_barrier();  // order LDS write -> read (free)

        for (int j = 0; j < m; ++j) {
            const float4 fa  = s_a[w][j];
            const float4 fb4 = s_b[w][j];
            const float4 fc  = s_c[w][j];
            // Contracted: w = fma(yp, A, xp*B) + C
            const float w0 = addrn(fmarn(yp, fa.x, mulrn(xp, fa.y)), fa.z);
            const float w1 = addrn(fmarn(yp, fa.w, mulrn(xp, fb4.x)), fb4.y);
            const float w2 = addrn(fmarn(yp, fb4.z, mulrn(xp, fb4.w)), fc.x);
            const float det = addrn(addrn(w0, w1), w2);
            bool ins;
            if (det > TINYF)       ins = (w0 > 0.f) && (w1 > 0.f) && (w2 > 0.f);
            else if (det < -TINYF) ins = (w0 < 0.f) && (w1 < 0.f) && (w2 < 0.f);
            else                   ins = false;
            // Early-z: zp >= min(z) - ~5e-5 (clipped weights sum ~1), so a
            // face with min(z) > bestz+ZEPS can neither win nor tie.
            const float minz = fminf(fminf(fc.y, fc.z), fc.w);
            if (ins && minz <= bestz + ZEPS) {
                float n0 = divrn(w0, det), n1 = divrn(w1, det), n2 = divrn(w2, det);
                n0 = frn(fminf(fmaxf(n0, 0.f), 1.f));
                n1 = frn(fminf(fmaxf(n1, 0.f), 1.f));
                n2 = frn(fminf(fmaxf(n2, 0.f), 1.f));
                float s = addrn(addrn(n0, n1), n2);
                s = (s > TINYF) ? s : 1.0f;
                n0 = divrn(n0, s); n1 = divrn(n1, s); n2 = divrn(n2, s);
                float iz = addrn(addrn(divrn(n0, fc.y), divrn(n1, fc.z)),
                                 divrn(n2, fc.w));
                iz = (fabsf(iz) > TINYF) ? iz : 1.0f;
                const float zp = divrn(1.0f, iz);
                if (zp > NEARP && zp < FARP) {
                    const int fi = s_i[w][j];
                    if (zp < bestz || (zp == bestz && fi < besti)) {
                        bestz = zp;
                        besti = fi;
                    }
                }
            }
        }
        __builtin_amdgcn_wave_barrier();  // scan done before next staging round
    }

    // Phase C: shade the winning face (R6-verified chain, unchanged).
    const float* fbase = faces + (size_t)b * F * 9;
    float r = 0.f, g = 0.f, bch = 0.f, alpha = 0.f, depth = FARP;
    if (besti >= 0) {
        const float* fp = fbase + (size_t)besti * 9;
        const float x0 = fp[0], y0 = fp[1], z0 = fp[2];
        const float x1 = fp[3], y1 = fp[4], z1 = fp[5];
        const float x2 = fp[6], y2 = fp[7], z2 = fp[8];
        const float w0 = addrn(fmarn(yp, subrn(x2, x1), mulrn(xp, subrn(y1, y2))),
                               fmarn(x1, y2, -mulrn(x2, y1)));
        const float w1 = addrn(fmarn(yp, subrn(x0, x2), mulrn(xp, subrn(y2, y0))),
                               fmarn(x2, y0, -mulrn(x0, y2)));
        const float w2 = addrn(fmarn(yp, subrn(x1, x0), mulrn(xp, subrn(y0, y1))),
                               fmarn(x0, y1, -mulrn(x1, y0)));
        const float det = addrn(addrn(w0, w1), w2);
        const float sd = (fabsf(det) > TINYF) ? det : 1.0f;
        float n0 = divrn(w0, sd), n1 = divrn(w1, sd), n2 = divrn(w2, sd);
        n0 = frn(fminf(fmaxf(n0, 0.f), 1.f));
        n1 = frn(fminf(fmaxf(n1, 0.f), 1.f));
        n2 = frn(fminf(fmaxf(n2, 0.f), 1.f));
        float s = addrn(addrn(n0, n1), n2);
        s = (s > TINYF) ? s : 1.0f;
        n0 = divrn(n0, s); n1 = divrn(n1, s); n2 = divrn(n2, s);
        float iz = addrn(addrn(divrn(n0, z0), divrn(n1, z1)), divrn(n2, z2));
        iz = (fabsf(iz) > TINYF) ? iz : 1.0f;
        const float zp = divrn(1.0f, iz);
        depth = zp;

        const float t0 = fminf(fmaxf(divrn(mulrn(mulrn(n0, 3.0f), zp), z0), 0.f), 2.999f);
        const float t1 = fminf(fmaxf(divrn(mulrn(mulrn(n1, 3.0f), zp), z1), 0.f), 2.999f);
        const float t2 = fminf(fmaxf(divrn(mulrn(mulrn(n2, 3.0f), zp), z2), 0.f), 2.999f);
        const float l0 = floorf(t0), l1 = floorf(t1), l2 = floorf(t2);
        const float fr0 = subrn(t0, l0), fr1 = subrn(t1, l1), fr2 = subrn(t2, l2);
        const int i0 = (int)l0, i1 = (int)l1, i2 = (int)l2;

        const float* tx = textures + (size_t)(b * F + besti) * 64 * 3;
        for (int d0 = 0; d0 < 2; ++d0)
            for (int d1 = 0; d1 < 2; ++d1)
                for (int d2 = 0; d2 < 2; ++d2) {
                    const float wg = mulrn(mulrn(d0 ? fr0 : subrn(1.0f, fr0),
                                                 d1 ? fr1 : subrn(1.0f, fr1)),
                                           d2 ? fr2 : subrn(1.0f, fr2));
                    const float* tp = tx + ((i0 + d0) * 16 + (i1 + d1) * 4 + (i2 + d2)) * 3;
                    r   = addrn(r,   mulrn(wg, tp[0]));
                    g   = addrn(g,   mulrn(wg, tp[1]));
                    bch = addrn(bch, mulrn(wg, tp[2]));
                }
        alpha = 1.0f;
    }

    float* op = out + (((size_t)b * IS + py) * IS + px) * 5;
    op[0] = r;
    op[1] = g;
    op[2] = bch;
    op[3] = alpha;
    op[4] = depth;
}

extern "C" void kernel_launch(void* const* d_in, const int* in_sizes, int n_in,
                              void* d_out, int out_size, void* d_ws, size_t ws_size,
                              hipStream_t stream) {
    const float* faces    = (const float*)d_in[0];
    const float* textures = (const float*)d_in[1];
    float* out = (float*)d_out;
    const int F = FCOUNT;
    const int B = in_sizes[0] / (F * 9);
    const int nbins = B * 1024;          // 32x32 bins per image

    int* counts = (int*)d_ws;                       // nbins ints
    int* gcount = counts + nbins;                   // B ints
    int* glist  = gcount + B;                       // B*GCAP ints
    int* lists  = glist + B * GCAP;                 // nbins*CAP ints
    float4* cA  = (float4*)(lists + (size_t)nbins * CAP);   // B*F float4
    float4* cB  = cA + (size_t)B * F;
    float4* cC  = cB + (size_t)B * F;

    hipMemsetAsync(counts, 0, (size_t)(nbins + B) * sizeof(int), stream);
    bin_kernel<<<dim3((B * F + 63) / 64), dim3(64), 0, stream>>>(
        faces, cA, cB, cC, counts, lists, gcount, glist, B, F);
    raster_kernel<<<dim3(B * 256), dim3(256), 0, stream>>>(
        faces, textures, cA, cB, cC, counts, lists, gcount, glist, out, B, F);
}